// Round 1
// baseline (1713.367 us; speedup 1.0000x reference)
//
#include <hip/hip_runtime.h>
#include <cstdint>
#include <cmath>

#define N_HEADS 16
#define I_DIM 128
#define H_DIM 128
#define B_SZ 16
#define T_SZ 512
#define G3 384          // 3*H
#define BT (B_SZ * T_SZ) // 8192
#define OUT_HN_OFFSET ((size_t)B_SZ * T_SZ * (N_HEADS * H_DIM)) // 16777216

// ---------------------------------------------------------------------------
// Kernel A: gates_x[n][bt][g] = dot(W_ih[n][g][:], x[bt, n*128:(n+1)*128]) + b_ih[n][g]
// One workgroup per (n, 64-bt chunk). 384 threads, one gate row per thread,
// W_ih row held in 128 VGPRs; x row broadcast from LDS (same-address b128 reads).
// ---------------------------------------------------------------------------
__global__ __launch_bounds__(384) void gates_x_kernel(
    const float* __restrict__ x, const float* __restrict__ w_ih,
    const float* __restrict__ b_ih, float* __restrict__ gates) {
  const int n = blockIdx.y;
  const int bt0 = blockIdx.x * 64;
  const int g = threadIdx.x; // 0..383

  __shared__ float xs[I_DIM];

  // Load this gate's weight row into registers (32 float4 = 128 VGPRs).
  const float4* w4 = (const float4*)(w_ih + ((size_t)n * G3 + g) * I_DIM);
  float4 wreg[32];
#pragma unroll
  for (int i = 0; i < 32; ++i) wreg[i] = w4[i];
  const float bih = b_ih[n * G3 + g];

  for (int i = 0; i < 64; ++i) {
    const int bt = bt0 + i;
    // Stage x row (128 floats, coalesced 512B by threads 0..31).
    if (g < 32) {
      ((float4*)xs)[g] = ((const float4*)(x + (size_t)bt * 2048 + n * I_DIM))[g];
    }
    __syncthreads();
    float a0 = 0.f, a1 = 0.f, a2 = 0.f, a3 = 0.f;
    const float4* xv = (const float4*)xs;
#pragma unroll
    for (int k = 0; k < 32; ++k) {
      float4 hv = xv[k];
      a0 += wreg[k].x * hv.x;
      a1 += wreg[k].y * hv.y;
      a2 += wreg[k].z * hv.z;
      a3 += wreg[k].w * hv.w;
    }
    gates[((size_t)n * BT + bt) * G3 + g] = ((a0 + a1) + (a2 + a3)) + bih;
    __syncthreads();
  }
}

// ---------------------------------------------------------------------------
// Kernel B: sequential GRU scan. One workgroup per (b,n) pair (256 total).
// 384 threads: thread g owns gate row g of W_hh (128 VGPRs), h lives in LDS.
// Per step: gh[g] = dot(W_hh[g], h) + b_hh[g]; then threads 0..127 do the
// elementwise GRU update and write output.
// ---------------------------------------------------------------------------
__global__ __launch_bounds__(384) void gru_scan_kernel(
    const float* __restrict__ h0, const float* __restrict__ w_hh,
    const float* __restrict__ b_hh, const float* __restrict__ gates,
    float* __restrict__ out) {
  const int b = blockIdx.x >> 4;
  const int n = blockIdx.x & 15;
  const int g = threadIdx.x; // 0..383

  __shared__ float h_lds[H_DIM];
  __shared__ float gh_lds[G3];

  const float4* w4 = (const float4*)(w_hh + ((size_t)n * G3 + g) * H_DIM);
  float4 wreg[32];
#pragma unroll
  for (int i = 0; i < 32; ++i) wreg[i] = w4[i];
  const float bhh = b_hh[n * G3 + g];

  if (g < H_DIM) h_lds[g] = h0[(size_t)b * 2048 + n * H_DIM + g];
  __syncthreads();

  const float* gx_base = gates + ((size_t)n * BT + (size_t)b * T_SZ) * G3;
  float* out_base = out + (size_t)b * T_SZ * 2048 + n * H_DIM;

  for (int t = 0; t < T_SZ; ++t) {
    const float* gx = gx_base + (size_t)t * G3;
    // Issue the (independent) gates_x loads early; latency hidden by the dot.
    float gxr = 0.f, gxz = 0.f, gxn = 0.f;
    if (g < H_DIM) {
      gxr = gx[g];
      gxz = gx[g + H_DIM];
      gxn = gx[g + 2 * H_DIM];
    }

    // gh[g] = dot(W_hh[g,:], h) ; h broadcast from LDS.
    float a0 = 0.f, a1 = 0.f, a2 = 0.f, a3 = 0.f;
    const float4* h4 = (const float4*)h_lds;
#pragma unroll
    for (int k = 0; k < 32; ++k) {
      float4 hv = h4[k];
      a0 += wreg[k].x * hv.x;
      a1 += wreg[k].y * hv.y;
      a2 += wreg[k].z * hv.z;
      a3 += wreg[k].w * hv.w;
    }
    gh_lds[g] = ((a0 + a1) + (a2 + a3)) + bhh;
    __syncthreads();

    if (g < H_DIM) {
      float r = 1.f / (1.f + __expf(-(gxr + gh_lds[g])));
      float z = 1.f / (1.f + __expf(-(gxz + gh_lds[g + H_DIM])));
      float nn = tanhf(gxn + r * gh_lds[g + 2 * H_DIM]);
      float hn = (1.f - z) * nn + z * h_lds[g];
      h_lds[g] = hn;
      out_base[(size_t)t * 2048 + g] = hn;
    }
    __syncthreads();
  }

  if (g < H_DIM) {
    out[OUT_HN_OFFSET + (size_t)b * 2048 + n * H_DIM + g] = h_lds[g];
  }
}

extern "C" void kernel_launch(void* const* d_in, const int* in_sizes, int n_in,
                              void* d_out, int out_size, void* d_ws, size_t ws_size,
                              hipStream_t stream) {
  const float* x    = (const float*)d_in[0]; // [B, T, N*I]
  const float* h0   = (const float*)d_in[1]; // [1, B, N*H]
  const float* w_ih = (const float*)d_in[2]; // [N, 3H, I]
  const float* w_hh = (const float*)d_in[3]; // [N, 3H, H]
  const float* b_ih = (const float*)d_in[4]; // [N, 3H]
  const float* b_hh = (const float*)d_in[5]; // [N, 3H]
  float* out = (float*)d_out;
  float* gates = (float*)d_ws; // [N][BT][3H] fp32 = 192 MB

  dim3 gridA(BT / 64, N_HEADS);
  gates_x_kernel<<<gridA, 384, 0, stream>>>(x, w_ih, b_ih, gates);
  gru_scan_kernel<<<256, 384, 0, stream>>>(h0, w_hh, b_hh, gates, out);
}

// Round 2
// 1308.948 us; speedup vs baseline: 1.3090x; 1.3090x over previous
//
#include <hip/hip_runtime.h>
#include <cstdint>
#include <cmath>

#define N_HEADS 16
#define I_DIM 128
#define H_DIM 128
#define B_SZ 16
#define T_SZ 512
#define G3 384           // 3*H
#define BT (B_SZ * T_SZ) // 8192
#define ROWS_A 128       // bt-rows per workgroup in gates_x
#define OUT_HN_OFFSET ((size_t)B_SZ * T_SZ * (N_HEADS * H_DIM)) // 16777216

// ---------------------------------------------------------------------------
// Kernel A: gates_x[n][bt][g] = dot(W_ih[n][g][:], x[bt, n*128:..]) + b_ih[n][g]
// 768 threads: pair (2g, 2g+1) splits gate g's K=128 dot into two 64-halves.
// Each thread keeps its 64-float weight half in 16 float4 VGPRs (loaded ONCE).
// __launch_bounds__(768,3): 12 waves/WG needs 3 waves/SIMD -> VGPR cap ~168,
// well above our ~120 footprint, so no rematerialization of the weight loads.
// ---------------------------------------------------------------------------
__global__ __launch_bounds__(768, 3) void gates_x_kernel(
    const float* __restrict__ x, const float* __restrict__ w_ih,
    const float* __restrict__ b_ih, float* __restrict__ gates) {
  const int n = blockIdx.y;
  const int bt0 = blockIdx.x * ROWS_A;
  const int tid = threadIdx.x;     // 0..767
  const int g = tid >> 1;          // gate row 0..383
  const int half = tid & 1;        // which 64-wide K-half

  __shared__ float xs[I_DIM];
  __shared__ float gs[G3];

  const float4* w4 =
      (const float4*)(w_ih + ((size_t)n * G3 + g) * I_DIM + half * 64);
  float4 w[16];
#pragma unroll
  for (int k = 0; k < 16; ++k) w[k] = w4[k];
  const float bih = b_ih[n * G3 + g];

  for (int i = 0; i < ROWS_A; ++i) {
    const int bt = bt0 + i;
    if (tid < 32) {
      ((float4*)xs)[tid] =
          ((const float4*)(x + (size_t)bt * 2048 + n * I_DIM))[tid];
    }
    __syncthreads();
    const float4* xv = (const float4*)xs + half * 16;
    float a0 = 0.f, a1 = 0.f, a2 = 0.f, a3 = 0.f;
#pragma unroll
    for (int k = 0; k < 16; ++k) {
      float4 hv = xv[k];
      a0 += w[k].x * hv.x;
      a1 += w[k].y * hv.y;
      a2 += w[k].z * hv.z;
      a3 += w[k].w * hv.w;
    }
    float a = (a0 + a1) + (a2 + a3);
    a += __shfl_xor(a, 1, 64);      // combine the two K-halves
    if (half == 0) gs[g] = a + bih; // stage in LDS for a coalesced store
    __syncthreads();
    if (tid < G3) gates[((size_t)n * BT + bt) * G3 + tid] = gs[tid];
  }
}

// ---------------------------------------------------------------------------
// Kernel B: sequential GRU scan. One WG per (b,n) (256 WGs = 1/CU).
// Same pair-split: thread pair (2g,2g+1) computes gh[g]; W_hh half-row
// register-resident. h lives in LDS; gates_x prefetched one step ahead.
// ---------------------------------------------------------------------------
__global__ __launch_bounds__(768, 3) void gru_scan_kernel(
    const float* __restrict__ h0, const float* __restrict__ w_hh,
    const float* __restrict__ b_hh, const float* __restrict__ gates,
    float* __restrict__ out) {
  const int b = blockIdx.x >> 4;
  const int n = blockIdx.x & 15;
  const int tid = threadIdx.x;
  const int g = tid >> 1;
  const int half = tid & 1;

  __shared__ float h_lds[H_DIM];
  __shared__ float gh_lds[G3];

  const float4* w4 =
      (const float4*)(w_hh + ((size_t)n * G3 + g) * H_DIM + half * 64);
  float4 w[16];
#pragma unroll
  for (int k = 0; k < 16; ++k) w[k] = w4[k];
  const float bhh = b_hh[n * G3 + g];

  if (tid < H_DIM) h_lds[tid] = h0[(size_t)b * 2048 + n * H_DIM + tid];

  const float* gx_base = gates + ((size_t)n * BT + (size_t)b * T_SZ) * G3;
  float* out_base = out + (size_t)b * T_SZ * 2048 + n * H_DIM;

  // Prefetch t=0 gates_x into registers.
  float gxr = 0.f, gxz = 0.f, gxn = 0.f;
  if (tid < H_DIM) {
    gxr = gx_base[tid];
    gxz = gx_base[tid + H_DIM];
    gxn = gx_base[tid + 2 * H_DIM];
  }
  __syncthreads();

  for (int t = 0; t < T_SZ; ++t) {
    // Prefetch next step's gates_x (latency hidden behind the dot + barrier).
    float pr = 0.f, pz = 0.f, pn = 0.f;
    const int tn = (t + 1 < T_SZ) ? t + 1 : t;
    if (tid < H_DIM) {
      const float* gx = gx_base + (size_t)tn * G3;
      pr = gx[tid];
      pz = gx[tid + H_DIM];
      pn = gx[tid + 2 * H_DIM];
    }

    // gh[g] = dot(W_hh[g,:], h): each thread does its 64-half, pair-reduce.
    const float4* hv4 = (const float4*)h_lds + half * 16;
    float a0 = 0.f, a1 = 0.f, a2 = 0.f, a3 = 0.f;
#pragma unroll
    for (int k = 0; k < 16; ++k) {
      float4 hv = hv4[k];
      a0 += w[k].x * hv.x;
      a1 += w[k].y * hv.y;
      a2 += w[k].z * hv.z;
      a3 += w[k].w * hv.w;
    }
    float a = (a0 + a1) + (a2 + a3);
    a += __shfl_xor(a, 1, 64);
    if (half == 0) gh_lds[g] = a + bhh;
    __syncthreads();

    if (tid < H_DIM) {
      const float r = 1.f / (1.f + __expf(-(gxr + gh_lds[tid])));
      const float z = 1.f / (1.f + __expf(-(gxz + gh_lds[tid + H_DIM])));
      const float targ = gxn + r * gh_lds[tid + 2 * H_DIM];
      // overflow-safe tanh via exp(-2|x|) <= 1
      const float e2 = __expf(-2.f * fabsf(targ));
      float nn = (1.f - e2) / (1.f + e2);
      nn = (targ < 0.f) ? -nn : nn;
      const float hn = (1.f - z) * nn + z * h_lds[tid];
      h_lds[tid] = hn;
      out_base[(size_t)t * 2048 + tid] = hn;
    }
    gxr = pr; gxz = pz; gxn = pn;
    __syncthreads();
  }

  if (tid < H_DIM) {
    out[OUT_HN_OFFSET + (size_t)b * 2048 + n * H_DIM + tid] = h_lds[tid];
  }
}

extern "C" void kernel_launch(void* const* d_in, const int* in_sizes, int n_in,
                              void* d_out, int out_size, void* d_ws, size_t ws_size,
                              hipStream_t stream) {
  const float* x    = (const float*)d_in[0]; // [B, T, N*I]
  const float* h0   = (const float*)d_in[1]; // [1, B, N*H]
  const float* w_ih = (const float*)d_in[2]; // [N, 3H, I]
  const float* w_hh = (const float*)d_in[3]; // [N, 3H, H]
  const float* b_ih = (const float*)d_in[4]; // [N, 3H]
  const float* b_hh = (const float*)d_in[5]; // [N, 3H]
  float* out = (float*)d_out;
  float* gates = (float*)d_ws; // [N][BT][3H] fp32 = 192 MB

  dim3 gridA(BT / ROWS_A, N_HEADS);
  gates_x_kernel<<<gridA, 768, 0, stream>>>(x, w_ih, b_ih, gates);
  gru_scan_kernel<<<256, 768, 0, stream>>>(h0, w_hh, b_hh, gates, out);
}

// Round 4
// 758.884 us; speedup vs baseline: 2.2577x; 1.7248x over previous
//
#include <hip/hip_runtime.h>
#include <cstdint>
#include <cmath>

#define N_HEADS 16
#define I_DIM 128
#define H_DIM 128
#define B_SZ 16
#define T_SZ 512
#define G3 384           // 3*H
#define BT (B_SZ * T_SZ) // 8192
#define LDW 136          // padded LDS row stride in bf16 (128+8): keeps 16B align, banks 2-way
#define OUT_HN_OFFSET ((size_t)B_SZ * T_SZ * (N_HEADS * H_DIM)) // 16777216

typedef __attribute__((ext_vector_type(8))) short bf16x8;
typedef __attribute__((ext_vector_type(4))) float f32x4;

static __device__ __forceinline__ unsigned short f2bf(float f) {
  unsigned int u = __float_as_uint(f);
  unsigned int r = (u + 0x7FFFu + ((u >> 16) & 1u)) >> 16; // RNE
  return (unsigned short)r;
}
static __device__ __forceinline__ uint2 pack4(float4 v) {
  uint2 p;
  p.x = (unsigned int)f2bf(v.x) | ((unsigned int)f2bf(v.y) << 16);
  p.y = (unsigned int)f2bf(v.z) | ((unsigned int)f2bf(v.w) << 16);
  return p;
}

// ---------------------------------------------------------------------------
// Kernel A: bf16 MFMA GEMM. Per head n: gates[8192x384] = X_n * W_ih[n]^T.
// WG = 256 thr (4 waves), tile = 64 (bt) x 128 (gates). fp32 inputs converted
// to bf16 during LDS staging; fp32 accumulate; fp32 gates store.
// LDS: Xs 64x136 bf16 (17 KB) + Ws 128x136 bf16 (34 KB) = 51 KB < 64 KB.
// Frag reads use the m89-verified 16x16x32 layouts:
//   A[m=lane&15][k=quad*8+j], B^T[n=lane&15][k=quad*8+j],
//   D[row m=quad*4+reg][col n=lane&15].
// ---------------------------------------------------------------------------
__global__ __launch_bounds__(256) void gates_x_mfma(
    const float* __restrict__ x, const float* __restrict__ w_ih,
    const float* __restrict__ b_ih, float* __restrict__ gates) {
  const int n = blockIdx.z;
  const int g0 = blockIdx.y * 128;
  const int bt0 = blockIdx.x * 64;
  const int tid = threadIdx.x;
  const int wave = tid >> 6;
  const int lane = tid & 63;
  const int m16 = lane & 15;
  const int quad = lane >> 4;

  __shared__ __align__(16) unsigned short Xs[64 * LDW];
  __shared__ __align__(16) unsigned short Ws[128 * LDW];

  // Stage X tile: 64 rows x 128 k. Thread t: row=t>>2, quarter q=t&3 (32 floats).
  {
    const int row = tid >> 2;
    const int q = tid & 3;
    const float4* xg = (const float4*)(x + (size_t)(bt0 + row) * 2048 + n * I_DIM) + q * 8;
#pragma unroll
    for (int i = 0; i < 8; ++i) {
      *(uint2*)&Xs[row * LDW + q * 32 + i * 4] = pack4(xg[i]);
    }
  }
  // Stage W tile: 128 gate-rows x 128 k. Thread t: row=t>>1, half h=t&1.
  {
    const int r = tid >> 1;
    const int h = tid & 1;
    const float4* wg =
        (const float4*)(w_ih + ((size_t)n * G3 + g0 + r) * I_DIM) + h * 16;
#pragma unroll
    for (int i = 0; i < 16; ++i) {
      *(uint2*)&Ws[r * LDW + h * 64 + i * 4] = pack4(wg[i]);
    }
  }
  __syncthreads();

  f32x4 acc[8];
#pragma unroll
  for (int j = 0; j < 8; ++j) acc[j] = (f32x4){0.f, 0.f, 0.f, 0.f};

#pragma unroll
  for (int kt = 0; kt < 4; ++kt) {
    const bf16x8 afrag =
        *(const bf16x8*)&Xs[(wave * 16 + m16) * LDW + kt * 32 + quad * 8];
#pragma unroll
    for (int j = 0; j < 8; ++j) {
      const bf16x8 bfrag =
          *(const bf16x8*)&Ws[(j * 16 + m16) * LDW + kt * 32 + quad * 8];
      acc[j] = __builtin_amdgcn_mfma_f32_16x16x32_bf16(afrag, bfrag, acc[j], 0, 0, 0);
    }
  }

  // Epilogue: bias + store. D[row=quad*4+r][col=m16].
#pragma unroll
  for (int j = 0; j < 8; ++j) {
    const int g = g0 + j * 16 + m16;
    const float bias = b_ih[n * G3 + g];
#pragma unroll
    for (int r = 0; r < 4; ++r) {
      const int bt = bt0 + wave * 16 + quad * 4 + r;
      gates[((size_t)n * BT + bt) * G3 + g] = acc[j][r] + bias;
    }
  }
}

// ---------------------------------------------------------------------------
// Kernel B: sequential GRU scan. One WG per (b,n). Pair (2g,2g+1) splits gate
// g's K=128 dot. Weight halves are pinned in VGPRs via an opaque asm fence
// (defeats LLVM's remat-instead-of-keep heuristic that gave VGPR_Count=44).
// ---------------------------------------------------------------------------
__global__ __launch_bounds__(768, 3) void gru_scan_kernel(
    const float* __restrict__ h0, const float* __restrict__ w_hh,
    const float* __restrict__ b_hh, const float* __restrict__ gates,
    float* __restrict__ out) {
  const int b = blockIdx.x >> 4;
  const int n = blockIdx.x & 15;
  const int tid = threadIdx.x;
  const int g = tid >> 1;
  const int half = tid & 1;

  __shared__ float h_lds[H_DIM];
  __shared__ float gh_lds[G3];

  const float4* w4 =
      (const float4*)(w_hh + ((size_t)n * G3 + g) * H_DIM + half * 64);
  float4 w[16];
#pragma unroll
  for (int k = 0; k < 16; ++k) w[k] = w4[k];
  // Opaque fence: values can no longer be rematerialized from memory, so the
  // allocator must keep all 64 weight VGPRs resident across the T-loop.
#pragma unroll
  for (int k = 0; k < 16; ++k) {
    asm volatile("" : "+v"(w[k].x), "+v"(w[k].y), "+v"(w[k].z), "+v"(w[k].w));
  }
  const float bhh = b_hh[n * G3 + g];

  if (tid < H_DIM) h_lds[tid] = h0[(size_t)b * 2048 + n * H_DIM + tid];

  const float* gx_base = gates + ((size_t)n * BT + (size_t)b * T_SZ) * G3;
  float* out_base = out + (size_t)b * T_SZ * 2048 + n * H_DIM;

  float gxr = 0.f, gxz = 0.f, gxn = 0.f;
  if (tid < H_DIM) {
    gxr = gx_base[tid];
    gxz = gx_base[tid + H_DIM];
    gxn = gx_base[tid + 2 * H_DIM];
  }
  __syncthreads();

  for (int t = 0; t < T_SZ; ++t) {
    float pr = 0.f, pz = 0.f, pn = 0.f;
    const int tn = (t + 1 < T_SZ) ? t + 1 : t;
    if (tid < H_DIM) {
      const float* gx = gx_base + (size_t)tn * G3;
      pr = gx[tid];
      pz = gx[tid + H_DIM];
      pn = gx[tid + 2 * H_DIM];
    }

    const float4* hv4 = (const float4*)h_lds + half * 16;
    float a0 = 0.f, a1 = 0.f, a2 = 0.f, a3 = 0.f;
#pragma unroll
    for (int k = 0; k < 16; ++k) {
      float4 hv = hv4[k];
      a0 += w[k].x * hv.x;
      a1 += w[k].y * hv.y;
      a2 += w[k].z * hv.z;
      a3 += w[k].w * hv.w;
    }
    float a = (a0 + a1) + (a2 + a3);
    a += __shfl_xor(a, 1, 64);
    if (half == 0) gh_lds[g] = a + bhh;
    __syncthreads();

    if (tid < H_DIM) {
      const float r = 1.f / (1.f + __expf(-(gxr + gh_lds[tid])));
      const float z = 1.f / (1.f + __expf(-(gxz + gh_lds[tid + H_DIM])));
      const float targ = gxn + r * gh_lds[tid + 2 * H_DIM];
      const float e2 = __expf(-2.f * fabsf(targ));
      float nn = (1.f - e2) / (1.f + e2);
      nn = (targ < 0.f) ? -nn : nn;
      const float hn = (1.f - z) * nn + z * h_lds[tid];
      h_lds[tid] = hn;
      out_base[(size_t)t * 2048 + tid] = hn;
    }
    gxr = pr; gxz = pz; gxn = pn;
    __syncthreads();
  }

  if (tid < H_DIM) {
    out[OUT_HN_OFFSET + (size_t)b * 2048 + n * H_DIM + tid] = h_lds[tid];
  }
}

extern "C" void kernel_launch(void* const* d_in, const int* in_sizes, int n_in,
                              void* d_out, int out_size, void* d_ws, size_t ws_size,
                              hipStream_t stream) {
  const float* x    = (const float*)d_in[0]; // [B, T, N*I]
  const float* h0   = (const float*)d_in[1]; // [1, B, N*H]
  const float* w_ih = (const float*)d_in[2]; // [N, 3H, I]
  const float* w_hh = (const float*)d_in[3]; // [N, 3H, H]
  const float* b_ih = (const float*)d_in[4]; // [N, 3H]
  const float* b_hh = (const float*)d_in[5]; // [N, 3H]
  float* out = (float*)d_out;
  float* gates = (float*)d_ws; // [N][BT][3H] fp32 = 192 MB

  dim3 gridA(BT / 64, G3 / 128, N_HEADS);
  gates_x_mfma<<<gridA, 256, 0, stream>>>(x, w_ih, b_ih, gates);
  gru_scan_kernel<<<256, 768, 0, stream>>>(h0, w_hh, b_hh, gates, out);
}

// Round 5
// 660.002 us; speedup vs baseline: 2.5960x; 1.1498x over previous
//
#include <hip/hip_runtime.h>
#include <cstdint>
#include <cmath>

#define N_HEADS 16
#define I_DIM 128
#define H_DIM 128
#define B_SZ 16
#define T_SZ 512
#define G3 384           // 3*H
#define BT (B_SZ * T_SZ) // 8192
#define LDW 136          // padded LDS row stride in bf16 (128+8)
#define OUT_HN_OFFSET ((size_t)B_SZ * T_SZ * (N_HEADS * H_DIM)) // 16777216

typedef __attribute__((ext_vector_type(8))) short bf16x8;
typedef __attribute__((ext_vector_type(4))) float f32x4;

static __device__ __forceinline__ unsigned short f2bf(float f) {
  unsigned int u = __float_as_uint(f);
  unsigned int r = (u + 0x7FFFu + ((u >> 16) & 1u)) >> 16; // RNE
  return (unsigned short)r;
}
static __device__ __forceinline__ float bf2f(unsigned short s) {
  return __uint_as_float((unsigned int)s << 16);
}
static __device__ __forceinline__ uint2 pack4(float4 v) {
  uint2 p;
  p.x = (unsigned int)f2bf(v.x) | ((unsigned int)f2bf(v.y) << 16);
  p.y = (unsigned int)f2bf(v.z) | ((unsigned int)f2bf(v.w) << 16);
  return p;
}

// ---------------------------------------------------------------------------
// Kernel A: bf16 MFMA GEMM, gates stored as bf16.
// Per head n: gates[8192x384] = X_n * W_ih[n]^T. WG = 256 thr (4 waves),
// X tile 64(bt)x128(k) staged ONCE, then loop over the three 128-gate blocks
// restaging only Ws (x HBM traffic 192->64 MB).
// ---------------------------------------------------------------------------
__global__ __launch_bounds__(256) void gates_x_mfma(
    const float* __restrict__ x, const float* __restrict__ w_ih,
    const float* __restrict__ b_ih, unsigned short* __restrict__ gates) {
  const int n = blockIdx.z;
  const int bt0 = blockIdx.x * 64;
  const int tid = threadIdx.x;
  const int wave = tid >> 6;
  const int lane = tid & 63;
  const int m16 = lane & 15;
  const int quad = lane >> 4;

  __shared__ __align__(16) unsigned short Xs[64 * LDW];
  __shared__ __align__(16) unsigned short Ws[128 * LDW];

  // Stage X tile: 64 rows x 128 k (thread t: row=t>>2, 32-float quarter t&3).
  {
    const int row = tid >> 2;
    const int q = tid & 3;
    const float4* xg =
        (const float4*)(x + (size_t)(bt0 + row) * 2048 + n * I_DIM) + q * 8;
#pragma unroll
    for (int i = 0; i < 8; ++i) {
      *(uint2*)&Xs[row * LDW + q * 32 + i * 4] = pack4(xg[i]);
    }
  }
  // Stage W block 0.
  {
    const int r = tid >> 1;
    const int h = tid & 1;
    const float4* wg =
        (const float4*)(w_ih + ((size_t)n * G3 + r) * I_DIM) + h * 16;
#pragma unroll
    for (int i = 0; i < 16; ++i) {
      *(uint2*)&Ws[r * LDW + h * 64 + i * 4] = pack4(wg[i]);
    }
  }
  __syncthreads();

  for (int gb = 0; gb < 3; ++gb) {
    f32x4 acc[8];
#pragma unroll
    for (int j = 0; j < 8; ++j) acc[j] = (f32x4){0.f, 0.f, 0.f, 0.f};

#pragma unroll
    for (int kt = 0; kt < 4; ++kt) {
      const bf16x8 afrag =
          *(const bf16x8*)&Xs[(wave * 16 + m16) * LDW + kt * 32 + quad * 8];
#pragma unroll
      for (int j = 0; j < 8; ++j) {
        const bf16x8 bfrag =
            *(const bf16x8*)&Ws[(j * 16 + m16) * LDW + kt * 32 + quad * 8];
        acc[j] =
            __builtin_amdgcn_mfma_f32_16x16x32_bf16(afrag, bfrag, acc[j], 0, 0, 0);
      }
    }

    // Epilogue: bias + bf16 store. D[row=quad*4+r][col=m16].
#pragma unroll
    for (int j = 0; j < 8; ++j) {
      const int g = gb * 128 + j * 16 + m16;
      const float bias = b_ih[n * G3 + g];
#pragma unroll
      for (int r = 0; r < 4; ++r) {
        const int bt = bt0 + wave * 16 + quad * 4 + r;
        gates[((size_t)n * BT + bt) * G3 + g] = f2bf(acc[j][r] + bias);
      }
    }

    if (gb < 2) {
      __syncthreads(); // all MFMA reads of Ws done before restage
      const int r = tid >> 1;
      const int h = tid & 1;
      const float4* wg =
          (const float4*)(w_ih + ((size_t)n * G3 + (gb + 1) * 128 + r) * I_DIM) +
          h * 16;
#pragma unroll
      for (int i = 0; i < 16; ++i) {
        *(uint2*)&Ws[r * LDW + h * 64 + i * 4] = pack4(wg[i]);
      }
      __syncthreads();
    }
  }
}

// ---------------------------------------------------------------------------
// Kernel B: sequential GRU scan. One WG per (b,n). 768 thr = 12 waves.
// Wave w handles gates [(w>>1)*64 .. +64) with K-half (w&1): per k-step the
// whole wave reads ONE float4 of h (wave-uniform address -> free broadcast).
// Weight half-rows (16 float4 = 64 VGPRs) register-resident: launch_bounds
// (768,1) gives the allocator >=170 VGPRs (R2/R4's (768,3) capped it at ~56
// and forced scratch spills -> L2-bound at ~590us). K-halves combined via a
// stride-1 LDS partial array fused into the elementwise update.
// ---------------------------------------------------------------------------
__global__ __launch_bounds__(768, 1) void gru_scan_kernel(
    const float* __restrict__ h0, const float* __restrict__ w_hh,
    const float* __restrict__ b_hh, const unsigned short* __restrict__ gates,
    float* __restrict__ out) {
  const int b = blockIdx.x >> 4;
  const int n = blockIdx.x & 15;
  const int tid = threadIdx.x;
  const int wave = tid >> 6;
  const int lane = tid & 63;
  const int half = wave & 1;
  const int g = ((wave >> 1) << 6) + lane; // 0..383

  __shared__ float h_lds[H_DIM];
  __shared__ float part[2][G3];

  const float4* w4 =
      (const float4*)(w_hh + ((size_t)n * G3 + g) * H_DIM + half * 64);
  float4 w[16];
#pragma unroll
  for (int k = 0; k < 16; ++k) w[k] = w4[k];
#pragma unroll
  for (int k = 0; k < 16; ++k) {
    asm volatile("" : "+v"(w[k].x), "+v"(w[k].y), "+v"(w[k].z), "+v"(w[k].w));
  }

  // Update-thread constants (threads 0..127 own h element `tid`).
  float bh0 = 0.f, bh1 = 0.f, bh2 = 0.f;
  if (tid < H_DIM) {
    bh0 = b_hh[n * G3 + tid];
    bh1 = b_hh[n * G3 + tid + 128];
    bh2 = b_hh[n * G3 + tid + 256];
    h_lds[tid] = h0[(size_t)b * 2048 + n * H_DIM + tid];
  }

  const unsigned short* gx_base = gates + ((size_t)n * BT + (size_t)b * T_SZ) * G3;
  float* out_base = out + (size_t)b * T_SZ * 2048 + n * H_DIM;

  float gxr = 0.f, gxz = 0.f, gxn = 0.f;
  if (tid < H_DIM) {
    gxr = bf2f(gx_base[tid]);
    gxz = bf2f(gx_base[tid + 128]);
    gxn = bf2f(gx_base[tid + 256]);
  }
  __syncthreads();

  for (int t = 0; t < T_SZ; ++t) {
    // Prefetch next step's gates_x (global latency hidden behind dot+barrier).
    float pr = 0.f, pz = 0.f, pn = 0.f;
    const int tn = (t + 1 < T_SZ) ? t + 1 : t;
    if (tid < H_DIM) {
      const unsigned short* gx = gx_base + (size_t)tn * G3;
      pr = bf2f(gx[tid]);
      pz = bf2f(gx[tid + 128]);
      pn = bf2f(gx[tid + 256]);
    }

    // Dot: wave-uniform h reads (single-address broadcast).
    const float4* h4 = (const float4*)h_lds + half * 16;
    float a0 = 0.f, a1 = 0.f, a2 = 0.f, a3 = 0.f;
#pragma unroll
    for (int k = 0; k < 16; ++k) {
      const float4 hv = h4[k];
      a0 += w[k].x * hv.x;
      a1 += w[k].y * hv.y;
      a2 += w[k].z * hv.z;
      a3 += w[k].w * hv.w;
    }
    part[half][g] = (a0 + a1) + (a2 + a3);
    __syncthreads();

    if (tid < H_DIM) {
      const float ghr = part[0][tid] + part[1][tid] + bh0;
      const float ghz = part[0][tid + 128] + part[1][tid + 128] + bh1;
      const float ghn = part[0][tid + 256] + part[1][tid + 256] + bh2;
      const float r = 1.f / (1.f + __expf(-(gxr + ghr)));
      const float z = 1.f / (1.f + __expf(-(gxz + ghz)));
      const float targ = gxn + r * ghn;
      const float e2 = __expf(-2.f * fabsf(targ));
      float nn = (1.f - e2) / (1.f + e2);
      nn = (targ < 0.f) ? -nn : nn;
      const float hn = (1.f - z) * nn + z * h_lds[tid];
      h_lds[tid] = hn;
      out_base[(size_t)t * 2048 + tid] = hn;
    }
    gxr = pr; gxz = pz; gxn = pn;
    __syncthreads();
  }

  if (tid < H_DIM) {
    out[OUT_HN_OFFSET + (size_t)b * 2048 + n * H_DIM + tid] = h_lds[tid];
  }
}

extern "C" void kernel_launch(void* const* d_in, const int* in_sizes, int n_in,
                              void* d_out, int out_size, void* d_ws, size_t ws_size,
                              hipStream_t stream) {
  const float* x    = (const float*)d_in[0]; // [B, T, N*I]
  const float* h0   = (const float*)d_in[1]; // [1, B, N*H]
  const float* w_ih = (const float*)d_in[2]; // [N, 3H, I]
  const float* w_hh = (const float*)d_in[3]; // [N, 3H, H]
  const float* b_ih = (const float*)d_in[4]; // [N, 3H]
  const float* b_hh = (const float*)d_in[5]; // [N, 3H]
  float* out = (float*)d_out;
  unsigned short* gates = (unsigned short*)d_ws; // [N][BT][3H] bf16 = 96 MB

  dim3 gridA(BT / 64, 1, N_HEADS);
  gates_x_mfma<<<gridA, 256, 0, stream>>>(x, w_ih, b_ih, gates);
  gru_scan_kernel<<<256, 768, 0, stream>>>(h0, w_hh, b_hh, gates, out);
}